// Round 8
// baseline (196.251 us; speedup 1.0000x reference)
//
#include <hip/hip_runtime.h>
#include <hip/hip_bf16.h>

typedef __bf16 bf16_t;
typedef __bf16 bf16x8 __attribute__((ext_vector_type(8)));
typedef float f32x4 __attribute__((ext_vector_type(4)));
typedef float f32x8 __attribute__((ext_vector_type(8)));
typedef float f32x16 __attribute__((ext_vector_type(16)));
typedef unsigned int u32;

#define GAS __attribute__((address_space(1)))
#define LAS __attribute__((address_space(3)))

#define B_N 32
#define T_N 2048
#define C_N 256
#define F_N 1024
#define NSPLIT 16
#define TSUB 128
#define NCHUNK 32
#define CHBYTES 32768
#define NITER 16            // 2 chunks per iteration

// ---------------- weight prep: build LDS-image layouts in ws ----------------
// W1 image per chunk ch (32 hidden rows): entry (kg 0..31, hl 0..31) 16B =
//   { bf16(W1[kg*8+j][ch*32+hl]) j=0..7 }  at  ch*32768 + kg*512 + hl*16
// W2 image per chunk: entry (G 0..3, cc 0..255) 16B at ch*32768 + 16384 + G*4096 + cc*16
//   element e = bf16(W2[ch*32 + perm(G,e)][cc]),  perm = (e&3) + 8*(2*(G>>1)+(e>>2)) + 4*(G&1)
__global__ __launch_bounds__(256) void k_prep(
    const float* __restrict__ W1, const float* __restrict__ W2,
    bf16_t* __restrict__ wsW) {
  int id = blockIdx.x * 256 + threadIdx.x;
  char* wb = (char*)wsW;
  if (id < 32768) {
    const int kg = id >> 10, h = id & 1023;
    const int ch = h >> 5, hl = h & 31;
    const float* src = W1 + (size_t)(kg << 3) * F_N + h;
    bf16x8 v;
#pragma unroll
    for (int j = 0; j < 8; ++j) v[j] = (bf16_t)src[(size_t)j * F_N];
    *(bf16x8*)(wb + (size_t)ch * CHBYTES + (kg << 9) + (hl << 4)) = v;
  } else {
    id -= 32768;
    const int Hg = id >> 8, cc = id & 255;
    const int ch = Hg >> 2, G = Hg & 3;
    bf16x8 v;
#pragma unroll
    for (int e = 0; e < 8; ++e) {
      const int hid = (ch << 5) + (e & 3) + ((((G >> 1) << 1) + (e >> 2)) << 3) + ((G & 1) << 2);
      v[e] = (bf16_t)W2[(size_t)hid * C_N + cc];
    }
    *(bf16x8*)(wb + (size_t)ch * CHBYTES + 16384 + (G << 12) + (cc << 4)) = v;
  }
}

// ---------------- stats pass 1: partial sum / sumsq over a T-slice ----------------
__global__ __launch_bounds__(256) void k_stats_partial(
    const float* __restrict__ x, float* __restrict__ psum, float* __restrict__ psq) {
  const int blk = blockIdx.x;
  const int b = blk / NSPLIT, s = blk % NSPLIT;
  const int tid = threadIdx.x;
  const int c4 = (tid & 63) << 2;
  const int tg = tid >> 6;
  const float* xb = x + ((size_t)b * T_N + (size_t)s * TSUB) * C_N;
  f32x4 sum = {0.f, 0.f, 0.f, 0.f};
  f32x4 sq  = {0.f, 0.f, 0.f, 0.f};
#pragma unroll 4
  for (int i = 0; i < TSUB / 4; ++i) {
    const int t = tg + (i << 2);
    f32x4 v = *(const f32x4*)(xb + (size_t)t * C_N + c4);
    sum += v;
    sq += v * v;
  }
  __shared__ f32x4 ls[256];
  __shared__ f32x4 lq[256];
  ls[tid] = sum; lq[tid] = sq;
  __syncthreads();
  if (tid < 64) {
    f32x4 S = ls[tid] + ls[tid + 64] + ls[tid + 128] + ls[tid + 192];
    f32x4 Q = lq[tid] + lq[tid + 64] + lq[tid + 128] + lq[tid + 192];
    *(f32x4*)(psum + (size_t)blk * C_N + c4) = S;
    *(f32x4*)(psq  + (size_t)blk * C_N + c4) = Q;
  }
}

// ---------------- stats pass 2: fused scale/shift (ddof=1) ----------------
__global__ __launch_bounds__(256) void k_stats_final(
    const float* __restrict__ psum, const float* __restrict__ psq,
    const float* __restrict__ gamma, const float* __restrict__ beta,
    float* __restrict__ As, float* __restrict__ Bs) {
  const int b = blockIdx.x, c = threadIdx.x;
  float S = 0.f, Q = 0.f;
#pragma unroll
  for (int s = 0; s < NSPLIT; ++s) {
    S += psum[(size_t)(b * NSPLIT + s) * C_N + c];
    Q += psq[(size_t)(b * NSPLIT + s) * C_N + c];
  }
  const float mu = S / (float)T_N;
  const float var = (Q - (float)T_N * mu * mu) / (float)(T_N - 1);
  const float a = rsqrtf(var + 1e-5f) * gamma[c];
  As[b * C_N + c] = a;
  Bs[b * C_N + c] = beta[c] - mu * a;
}

// ---------------- fused FFN: M=32/wave, 2 chunks per barrier interval,
// GEMM2(c0) interleaved 1:1 with GEMM1(c1) to fill the serial-chain bubbles,
// setprio around MFMA clusters, pair-wise LDS double buffer (4 slots). ----------------
__global__ __launch_bounds__(512, 2) void k_ffn(
    const float* __restrict__ x, const float* __restrict__ As,
    const float* __restrict__ Bs, const float* __restrict__ b1,
    const float* __restrict__ b2, const bf16_t* __restrict__ wsW,
    float* __restrict__ out) {
  __shared__ __attribute__((aligned(128))) unsigned char lds[4 * CHBYTES + 4096];
  float* b1lds = (float*)(lds + 4 * CHBYTES);

  const int tid = threadIdx.x;            // 0..511, 8 waves
  const int lane = tid & 63;
  const int w = tid >> 6;
  const int l31 = lane & 31;
  const int g = lane >> 5;

  const int tok0 = blockIdx.x << 8;       // 256 tokens / block
  const int b = blockIdx.x >> 3;          // 8 blocks per batch row
  const int t0 = tok0 + (w << 5);         // this wave's 32 tokens

  const char* wsb = (const char*)wsW;

  // stage chunk pair {0,1} -> half 0 (8 x 16B per thread)
#pragma unroll
  for (int j = 0; j < 8; ++j) {
    const int off = (j << 13) + (tid << 4);
    __builtin_amdgcn_global_load_lds((const GAS u32*)(wsb + off),
                                     (LAS u32*)(&lds[off]), 16, 0, 0);
  }

  // b1 -> LDS (1024 f32, 2 per thread)
  {
    const int i2 = tid << 1;
    b1lds[i2] = b1[i2];
    b1lds[i2 + 1] = b1[i2 + 1];
  }

  // prologue: normalized h fragments (64 VGPR)
  bf16x8 hfrag[16];
  {
    const float* ar = As + b * C_N;
    const float* br = Bs + b * C_N;
    const float* xrow = x + (size_t)(t0 + l31) * C_N;
#pragma unroll
    for (int ks = 0; ks < 16; ++ks) {
      const int c0 = (ks << 4) + (g << 3);
      f32x8 xv = *(const f32x8*)(xrow + c0);
      f32x8 av = *(const f32x8*)(ar + c0);
      f32x8 bv = *(const f32x8*)(br + c0);
      f32x8 hv = xv * av + bv;
#pragma unroll
      for (int e = 0; e < 8; ++e) hfrag[ks][e] = (bf16_t)hv[e];
    }
  }

  f32x16 accO[8];
#pragma unroll
  for (int nb = 0; nb < 8; ++nb)
#pragma unroll
    for (int e = 0; e < 16; ++e) accO[nb][e] = 0.f;

  __syncthreads();   // pair {0,1} staged, b1 visible

#pragma unroll 1
  for (int it = 0; it < NITER; ++it) {
    const int half = it & 1;
    const unsigned char* cbase = &lds[half ? 2 * CHBYTES : 0];

    // stage next pair into the other half (lands before this iter's barrier)
    if (it + 1 < NITER) {
      const char* gsrc = wsb + (size_t)(it + 1) * (2 * CHBYTES);
      unsigned char* ldst = &lds[half ? 0 : 2 * CHBYTES];
#pragma unroll
      for (int j = 0; j < 8; ++j) {
        const int off = (j << 13) + (tid << 4);
        __builtin_amdgcn_global_load_lds((const GAS u32*)(gsrc + off),
                                         (LAS u32*)(ldst + off), 16, 0, 0);
      }
    }

    const unsigned char* W1a = cbase;                    // chunk c0 = 2it
    const unsigned char* W2a = cbase + 16384;
    const unsigned char* W1b = cbase + CHBYTES;          // chunk c1 = 2it+1
    const unsigned char* W2b = cbase + CHBYTES + 16384;

    // ---- GEMM1(c0): serial D1 chain (exposed; c1's chain will be covered) ----
    f32x16 D1;
#pragma unroll
    for (int e = 0; e < 16; ++e) D1[e] = 0.f;
    __builtin_amdgcn_s_setprio(1);
#pragma unroll
    for (int ks = 0; ks < 16; ++ks) {
      const bf16x8 wf = *(const bf16x8*)(W1a + ((((ks << 1) + g) << 9) + (l31 << 4)));
      D1 = __builtin_amdgcn_mfma_f32_32x32x16_bf16(wf, hfrag[ks], D1, 0, 0, 0);
    }
    __builtin_amdgcn_s_setprio(0);

    // af0: bias + ReLU + cast (reg r holds hid = (r&3)+8*(r>>2)+4g)
    bf16x8 af0[2];
    {
      f32x4 b1q[4];
#pragma unroll
      for (int q = 0; q < 4; ++q)
        b1q[q] = *(const f32x4*)(b1lds + ((2 * it) << 5) + (g << 2) + (q << 3));
#pragma unroll
      for (int r = 0; r < 16; ++r) {
        float v = D1[r] + b1q[r >> 2][r & 3];
        v = v > 0.f ? v : 0.f;
        af0[r >> 3][r & 7] = (bf16_t)v;
      }
    }

    // ---- GEMM1(c1) 1:1 interleaved with GEMM2(c0): the 16 independent
    // GEMM2 chains fill the serial D1 chain's dependency bubbles ----
#pragma unroll
    for (int e = 0; e < 16; ++e) D1[e] = 0.f;
    __builtin_amdgcn_s_setprio(1);
#pragma unroll
    for (int ks = 0; ks < 16; ++ks) {
      const bf16x8 wf = *(const bf16x8*)(W1b + ((((ks << 1) + g) << 9) + (l31 << 4)));
      D1 = __builtin_amdgcn_mfma_f32_32x32x16_bf16(wf, hfrag[ks], D1, 0, 0, 0);
      const int s = ks >> 3, nb = ks & 7;
      const bf16x8 wf2 = *(const bf16x8*)(W2a + ((((s << 1) + g) << 12) + (nb << 9) + (l31 << 4)));
      accO[nb] = __builtin_amdgcn_mfma_f32_32x32x16_bf16(af0[s], wf2, accO[nb], 0, 0, 0);
    }
    __builtin_amdgcn_s_setprio(0);

    // af1
    bf16x8 af1[2];
    {
      f32x4 b1q[4];
#pragma unroll
      for (int q = 0; q < 4; ++q)
        b1q[q] = *(const f32x4*)(b1lds + ((2 * it + 1) << 5) + (g << 2) + (q << 3));
#pragma unroll
      for (int r = 0; r < 16; ++r) {
        float v = D1[r] + b1q[r >> 2][r & 3];
        v = v > 0.f ? v : 0.f;
        af1[r >> 3][r & 7] = (bf16_t)v;
      }
    }

    // ---- GEMM2(c1): 16 independent chains ----
    __builtin_amdgcn_s_setprio(1);
#pragma unroll
    for (int s = 0; s < 2; ++s) {
#pragma unroll
      for (int nb = 0; nb < 8; ++nb) {
        const bf16x8 wf2 = *(const bf16x8*)(W2b + ((((s << 1) + g) << 12) + (nb << 9) + (l31 << 4)));
        accO[nb] = __builtin_amdgcn_mfma_f32_32x32x16_bf16(af1[s], wf2, accO[nb], 0, 0, 0);
      }
    }
    __builtin_amdgcn_s_setprio(0);

    // stage loads (issued ~2 chunks ago) must land; then release buffers
    if (it + 1 < NITER) {
      asm volatile("s_waitcnt vmcnt(0)\n\ts_barrier" ::: "memory");
    }
  }

  // epilogue: out = accO + b2 + x   (token = t0 + 4g + rr + 8q, col = nb*32 + l31)
  {
    const float* xbase = x + (size_t)(t0 + (g << 2)) * C_N;
    float* obase = out + (size_t)(t0 + (g << 2)) * C_N;
#pragma unroll
    for (int nb = 0; nb < 8; ++nb) {
      const int c = (nb << 5) + l31;
      const float b2v = b2[c];
#pragma unroll
      for (int q = 0; q < 4; ++q) {
#pragma unroll
        for (int rr = 0; rr < 4; ++rr) {
          const size_t idx = (size_t)((q << 3) + rr) * C_N + c;
          obase[idx] = accO[nb][(q << 2) + rr] + b2v + xbase[idx];
        }
      }
    }
  }
}

extern "C" void kernel_launch(void* const* d_in, const int* in_sizes, int n_in,
                              void* d_out, int out_size, void* d_ws, size_t ws_size,
                              hipStream_t stream) {
  const float* x     = (const float*)d_in[0];
  const float* gamma = (const float*)d_in[1];
  const float* beta  = (const float*)d_in[2];
  const float* W1    = (const float*)d_in[3];
  const float* b1    = (const float*)d_in[4];
  const float* W2    = (const float*)d_in[5];
  const float* b2    = (const float*)d_in[6];
  float* out = (float*)d_out;

  char* ws = (char*)d_ws;
  bf16_t* wsW  = (bf16_t*)ws;                           // 1 MB
  float* psum  = (float*)(ws + (1024 << 10));           // 512 KB
  float* psq   = (float*)(ws + (1536 << 10));           // 512 KB
  float* As    = (float*)(ws + (2048 << 10));           // 32 KB
  float* Bs    = (float*)(ws + (2048 << 10) + (32 << 10));

  k_prep<<<256, 256, 0, stream>>>(W1, W2, wsW);
  k_stats_partial<<<B_N * NSPLIT, 256, 0, stream>>>(x, psum, psq);
  k_stats_final<<<B_N, 256, 0, stream>>>(psum, psq, gamma, beta, As, Bs);
  k_ffn<<<256, 512, 0, stream>>>(x, As, Bs, b1, b2, wsW, out);
}